// Round 1
// baseline (47.732 us; speedup 1.0000x reference)
//
#include <hip/hip_runtime.h>

#define NUM_LABELS 20
#define N_PIX 4096
#define C_DIM 16
#define BATCH 4
#define TILE 64
#define NTILE (N_PIX / TILE)              // 64
#define TPAIRS (NTILE * (NTILE + 1) / 2)  // 2080

// ---------------- Kernel A: center+normalize per pixel, histogram, weights --
__global__ __launch_bounds__(1024) void prep_kernel(
    const float* __restrict__ emb,   // [B][C][N]
    const int*   __restrict__ lab,   // [B][N]
    float* __restrict__ e_out,       // [B][C][N]
    float* __restrict__ w_out)       // [B][N]
{
    const int b = blockIdx.x;
    const int t = threadIdx.x;
    __shared__ int cnt[NUM_LABELS];
    if (t < NUM_LABELS) cnt[t] = 0;
    __syncthreads();

    const float* xb = emb + (size_t)b * C_DIM * N_PIX;
    const int*   yb = lab + (size_t)b * N_PIX;
    float*       eb = e_out + (size_t)b * C_DIM * N_PIX;

    for (int n = t; n < N_PIX; n += 1024) {
        float v[C_DIM];
        float s = 0.f;
#pragma unroll
        for (int c = 0; c < C_DIM; ++c) { v[c] = xb[c * N_PIX + n]; s += v[c]; }
        const float mean = s * (1.0f / C_DIM);
        float ss = 0.f;
#pragma unroll
        for (int c = 0; c < C_DIM; ++c) { v[c] -= mean; ss += v[c] * v[c]; }
        const float nrm = sqrtf(ss);
        const float inv = (nrm > 0.f) ? (1.0f / nrm) : 0.f;
#pragma unroll
        for (int c = 0; c < C_DIM; ++c) eb[c * N_PIX + n] = v[c] * inv;
        atomicAdd(&cnt[yb[n]], 1);
    }
    __syncthreads();
    for (int n = t; n < N_PIX; n += 1024) {
        w_out[(size_t)b * N_PIX + n] = 1.0f / (float)cnt[yb[n]];
    }
}

// ---------------- Kernel B: pairwise loss over upper-triangle 64x64 tiles ---
__global__ __launch_bounds__(256) void pair_kernel(
    const float* __restrict__ e,     // [B][C][N]
    const float* __restrict__ w,     // [B][N]
    const int*   __restrict__ lab,   // [B][N]
    float* __restrict__ partials)    // [B*TPAIRS]
{
    const int k0 = blockIdx.x % TPAIRS;
    const int b  = blockIdx.x / TPAIRS;

    // decode upper-triangle tile pair (ti <= tj)
    const float nn = (float)NTILE;
    int ti = (int)(((2.f * nn + 1.f) -
                    sqrtf((2.f * nn + 1.f) * (2.f * nn + 1.f) - 8.f * (float)k0)) * 0.5f);
    if (ti < 0) ti = 0;
    if (ti > NTILE - 1) ti = NTILE - 1;
    auto rowoff = [](int r) { return r * NTILE - (r * (r - 1)) / 2; };
    while (ti > 0 && k0 < rowoff(ti)) --ti;
    while (ti < NTILE - 1 && k0 >= rowoff(ti + 1)) ++ti;
    const int tj = ti + (k0 - rowoff(ti));
    const bool diag = (ti == tj);

    __shared__ float eI[C_DIM][TILE];
    __shared__ float eJ[C_DIM][TILE];
    __shared__ float wI[TILE], wJ[TILE];
    __shared__ int   yI[TILE], yJ[TILE];

    const int t = threadIdx.x;
    const size_t ebase = (size_t)b * C_DIM * N_PIX;
    for (int idx = t; idx < C_DIM * TILE; idx += 256) {
        const int c = idx >> 6;
        const int i = idx & 63;
        eI[c][i] = e[ebase + (size_t)c * N_PIX + ti * TILE + i];
        eJ[c][i] = e[ebase + (size_t)c * N_PIX + tj * TILE + i];
    }
    if (t < TILE) {
        wI[t] = w[(size_t)b * N_PIX + ti * TILE + t];
        yI[t] = lab[(size_t)b * N_PIX + ti * TILE + t];
    } else if (t < 2 * TILE) {
        const int u = t - TILE;
        wJ[u] = w[(size_t)b * N_PIX + tj * TILE + u];
        yJ[u] = lab[(size_t)b * N_PIX + tj * TILE + u];
    }
    __syncthreads();

    const int tI = t >> 4;  // 0..15  (i group of 4)
    const int tJ = t & 15;  // 0..15  (j group of 4)

    float acc[4][4];
#pragma unroll
    for (int a = 0; a < 4; ++a)
#pragma unroll
        for (int q = 0; q < 4; ++q) acc[a][q] = 0.f;

#pragma unroll
    for (int c = 0; c < C_DIM; ++c) {
        const float4 av = *reinterpret_cast<const float4*>(&eI[c][tI * 4]);
        const float4 bv = *reinterpret_cast<const float4*>(&eJ[c][tJ * 4]);
        const float aa[4] = {av.x, av.y, av.z, av.w};
        const float bb[4] = {bv.x, bv.y, bv.z, bv.w};
#pragma unroll
        for (int a = 0; a < 4; ++a)
#pragma unroll
            for (int q = 0; q < 4; ++q) acc[a][q] = fmaf(aa[a], bb[q], acc[a][q]);
    }

    float sum = 0.f;
#pragma unroll
    for (int a = 0; a < 4; ++a) {
        const int i = tI * 4 + a;
        const int   ya = yI[i];
        const float wa = wI[i];
#pragma unroll
        for (int q = 0; q < 4; ++q) {
            const int j = tJ * 4 + q;
            const float d = acc[a][q];
            const float loss = (ya == yJ[j]) ? fmaxf(0.5f - 0.5f * d, 0.f)
                                             : fmaxf(0.5f * d, 0.f);
            float f;
            if (diag) f = (i < j) ? 2.f : ((i == j) ? 1.f : 0.f);
            else      f = 2.f;
            sum += f * wa * wJ[j] * loss;
        }
    }

    // block reduction
    __shared__ float red[256];
    red[t] = sum;
    __syncthreads();
#pragma unroll
    for (int s = 128; s > 0; s >>= 1) {
        if (t < s) red[t] += red[t + s];
        __syncthreads();
    }
    if (t == 0) partials[blockIdx.x] = red[0];
}

// ---------------- Kernel C: deterministic final reduce ----------------------
__global__ __launch_bounds__(256) void reduce_kernel(
    const float* __restrict__ partials, int n, float* __restrict__ out)
{
    __shared__ double sd[256];
    const int t = threadIdx.x;
    double s = 0.0;
    for (int i = t; i < n; i += 256) s += (double)partials[i];
    sd[t] = s;
    __syncthreads();
#pragma unroll
    for (int k = 128; k > 0; k >>= 1) {
        if (t < k) sd[t] += sd[t + k];
        __syncthreads();
    }
    if (t == 0) out[0] = (float)(sd[0] * (1.0 / (double)N_PIX));
}

extern "C" void kernel_launch(void* const* d_in, const int* in_sizes, int n_in,
                              void* d_out, int out_size, void* d_ws, size_t ws_size,
                              hipStream_t stream) {
    const float* emb = (const float*)d_in[0];
    const int*   lab = (const int*)d_in[1];
    float* out = (float*)d_out;

    float* ws = (float*)d_ws;
    float* e_buf = ws;                                 // B*C*N = 262144 floats
    float* w_buf = e_buf + (size_t)BATCH * C_DIM * N_PIX;  // B*N = 16384 floats
    float* partials = w_buf + (size_t)BATCH * N_PIX;       // B*TPAIRS = 8320 floats

    prep_kernel<<<BATCH, 1024, 0, stream>>>(emb, lab, e_buf, w_buf);
    pair_kernel<<<BATCH * TPAIRS, 256, 0, stream>>>(e_buf, w_buf, lab, partials);
    reduce_kernel<<<1, 256, 0, stream>>>(partials, BATCH * TPAIRS, out);
}